// Round 1
// baseline (466.817 us; speedup 1.0000x reference)
//
#include <hip/hip_runtime.h>
#include <hip/hip_bf16.h>
#include <hip/hip_fp16.h>

#define NN   10000
#define FIN  512
#define FOUT 256
#define NPAD 10048
#define LRA  0.2f

typedef __attribute__((ext_vector_type(4))) float    f32x4;
typedef __attribute__((ext_vector_type(4))) int      i32x4;
typedef __attribute__((ext_vector_type(8))) _Float16 f16x8;
typedef __attribute__((ext_vector_type(8))) short    bf16x8;
typedef __attribute__((ext_vector_type(4))) short    bf16x4;

static __device__ __forceinline__ short f2bf(float x) {
  unsigned u = __builtin_bit_cast(unsigned, x);
  u += 0x7fffu + ((u >> 16) & 1u);   // RNE; x is always finite here
  return (short)(u >> 16);
}

// K0: Wt[c][k] = f16(W[k][c])   (512x256 -> 256x512)
__global__ __launch_bounds__(256) void k0_wt(const float* __restrict__ W,
                                             _Float16* __restrict__ Wt) {
  int idx = blockIdx.x * 256 + threadIdx.x;   // 131072 total
  int k = idx >> 8, c = idx & 255;
  Wt[(size_t)c * FIN + k] = (_Float16)W[(size_t)k * FOUT + c];
}

// K1: Wh[10000][256] = h @ W  via f16 MFMA, fp32 accum. BM=64, BN=256, 4 waves n-split.
__global__ __launch_bounds__(256) void k1_wh(const float* __restrict__ h,
                                             const _Float16* __restrict__ Wt,
                                             float* __restrict__ Wh) {
  const int r0 = blockIdx.x * 64;
  const int t = threadIdx.x;
  const int w = t >> 6, l = t & 63;
  const int lr = l & 15, lq = l >> 4;
  f32x4 acc[4][4];
#pragma unroll
  for (int m = 0; m < 4; ++m)
#pragma unroll
    for (int n = 0; n < 4; ++n)
#pragma unroll
      for (int q = 0; q < 4; ++q) acc[m][n][q] = 0.f;

  for (int kk = 0; kk < FIN; kk += 32) {
    f16x8 af[4];
#pragma unroll
    for (int m = 0; m < 4; ++m) {
      int gr = r0 + m * 16 + lr;
      if (gr < NN) {
        const f32x4* p = (const f32x4*)(h + (size_t)gr * FIN + kk + lq * 8);
        f32x4 v0 = p[0], v1 = p[1];
#pragma unroll
        for (int i = 0; i < 4; ++i) { af[m][i] = (_Float16)v0[i]; af[m][i + 4] = (_Float16)v1[i]; }
      } else {
#pragma unroll
        for (int i = 0; i < 8; ++i) af[m][i] = (_Float16)0.f;
      }
    }
#pragma unroll
    for (int n = 0; n < 4; ++n) {
      int gc = w * 64 + n * 16 + lr;
      f16x8 bf = *(const f16x8*)(Wt + (size_t)gc * FIN + kk + lq * 8);
#pragma unroll
      for (int m = 0; m < 4; ++m)
        acc[m][n] = __builtin_amdgcn_mfma_f32_16x16x32_f16(af[m], bf, acc[m][n], 0, 0, 0);
    }
  }
#pragma unroll
  for (int m = 0; m < 4; ++m)
#pragma unroll
    for (int n = 0; n < 4; ++n)
#pragma unroll
      for (int q = 0; q < 4; ++q) {
        int gr = r0 + m * 16 + lq * 4 + q;
        if (gr < NN) Wh[(size_t)gr * FOUT + w * 64 + n * 16 + lr] = acc[m][n][q];
      }
}

// K2: e1[i]=Wh[i,:]@a1, e2[i]=Wh[i,:]@a2 (zero-padded to 10048), and
//     WhT[c][r] = bf16(Wh[r][c]) with row stride NPAD (pad cols zeroed).
__global__ __launch_bounds__(256) void k2_et(const float* __restrict__ Wh,
                                             const float* __restrict__ a,
                                             float* __restrict__ e1,
                                             float* __restrict__ e2,
                                             short* __restrict__ WhT) {
  __shared__ float tile[64][65];
  const int r0 = blockIdx.x * 64;
  const int t = threadIdx.x;
  {
    int r = r0 + (t >> 2);
    int sub = t & 3;
    float s1 = 0.f, s2 = 0.f;
    if (r < NN) {
      for (int i = 0; i < 64; ++i) {
        int c = sub + 4 * i;
        float v = Wh[(size_t)r * FOUT + c];
        s1 += v * a[c];
        s2 += v * a[FOUT + c];
      }
    }
    s1 += __shfl_xor(s1, 1); s1 += __shfl_xor(s1, 2);
    s2 += __shfl_xor(s2, 1); s2 += __shfl_xor(s2, 2);
    if (sub == 0) {                 // r <= 10047 < NPAD
      e1[r] = (r < NN) ? s1 : 0.f;
      e2[r] = (r < NN) ? s2 : 0.f;
    }
  }
  for (int c0 = 0; c0 < FOUT; c0 += 64) {
    __syncthreads();
#pragma unroll
    for (int i = 0; i < 16; ++i) {
      int e = t + 256 * i;
      int row = e >> 6, col = e & 63;
      int grd = r0 + row;
      tile[row][col] = (grd < NN) ? Wh[(size_t)grd * FOUT + c0 + col] : 0.f;
    }
    __syncthreads();
#pragma unroll
    for (int i = 0; i < 16; ++i) {
      int e = t + 256 * i;
      int c = e >> 6, rr = e & 63;
      WhT[(size_t)(c0 + c) * NPAD + r0 + rr] = f2bf(tile[rr][c]);
    }
  }
}

// K3: fused masked-softmax @ Wh.  BM=32 rows/block, 512 threads (8 waves n-split 32),
// j-tiles of 64, P in XOR-swizzled LDS, 1-tile register prefetch of adj/e2.
__global__ __launch_bounds__(512) void k3_main(const int* __restrict__ adj,
                                               const float* __restrict__ e1,
                                               const float* __restrict__ e2,
                                               const short* __restrict__ WhT,
                                               float* __restrict__ out) {
  __shared__ __align__(16) char Plds[32 * 128];   // 32 rows x 64 bf16
  __shared__ float rowsum[32];
  const int r0 = blockIdx.x * 32;
  const int t = threadIdx.x;
  const int w = t >> 6, l = t & 63;
  const int lr = l & 15, lq = l >> 4;
  const int prow = t >> 4;        // 0..31
  const int psub = t & 15;        // 16 threads/row, 4 cols each
  const int gr = r0 + prow;
  const bool rowok = (gr < NN);
  const float e1v = rowok ? e1[gr] : 0.f;
  const size_t adjrow = (size_t)gr * NN;
  float rs = 0.f;
  f32x4 acc[2][2];
#pragma unroll
  for (int m = 0; m < 2; ++m)
#pragma unroll
    for (int n = 0; n < 2; ++n)
#pragma unroll
      for (int q = 0; q < 4; ++q) acc[m][n][q] = 0.f;

  const int NT = (NN + 63) / 64;  // 157
  i32x4 av; f32x4 ev;
#pragma unroll
  for (int i = 0; i < 4; ++i) { av[i] = 0; ev[i] = 0.f; }
  {   // prologue: tile 0 (full tile, always in range)
    int jbase = psub * 4;
    if (rowok) av = *(const i32x4*)(adj + adjrow + jbase);
    ev = *(const f32x4*)(e2 + jbase);
  }

  for (int jt = 0; jt < NT; ++jt) {
    const int j0 = jt * 64;
    // ---- compute p from prefetched regs ----
    bf16x4 pfrag;
#pragma unroll
    for (int i = 0; i < 4; ++i) {
      float s = e1v + ev[i];
      s = (s > 0.f) ? s : (LRA * s);
      float p = (av[i] > 0) ? __expf(s) : 0.f;
      rs += p;
      pfrag[i] = f2bf(p);
    }
    // ---- prefetch next tile ----
    if (jt + 1 < NT) {
      int jn = j0 + 64 + psub * 4;
      i32x4 nav;
#pragma unroll
      for (int i = 0; i < 4; ++i) nav[i] = 0;
      if (rowok) {
        if (j0 + 128 <= NN) nav = *(const i32x4*)(adj + adjrow + jn);
        else {
#pragma unroll
          for (int i = 0; i < 4; ++i) nav[i] = (jn + i < NN) ? adj[adjrow + jn + i] : 0;
        }
      }
      f32x4 nev = *(const f32x4*)(e2 + jn);  // e2 zero-padded to NPAD
      av = nav; ev = nev;
    }
    __syncthreads();   // previous MFMA reads of Plds complete
    *(bf16x4*)(Plds + prow * 128 + ((psub * 8) ^ ((prow & 7) << 4))) = pfrag;
    __syncthreads();   // P tile visible
    // ---- MFMA: acc += P(32x64) @ WhT^T(64x32 cols of this wave) ----
#pragma unroll
    for (int kt = 0; kt < 2; ++kt) {
      const int boff = ((kt * 4 + lq) << 4) ^ ((lr & 7) << 4);
      bf16x8 a0 = *(const bf16x8*)(Plds + lr * 128 + boff);
      bf16x8 a1 = *(const bf16x8*)(Plds + (16 + lr) * 128 + boff);
#pragma unroll
      for (int n = 0; n < 2; ++n) {
        int col = w * 32 + n * 16 + lr;
        bf16x8 bv = *(const bf16x8*)(WhT + (size_t)col * NPAD + j0 + kt * 32 + lq * 8);
        acc[0][n] = __builtin_amdgcn_mfma_f32_16x16x32_bf16(a0, bv, acc[0][n], 0, 0, 0);
        acc[1][n] = __builtin_amdgcn_mfma_f32_16x16x32_bf16(a1, bv, acc[1][n], 0, 0, 0);
      }
    }
  }
  // ---- row sums (16 threads per row are consecutive lanes) ----
  rs += __shfl_xor(rs, 1); rs += __shfl_xor(rs, 2);
  rs += __shfl_xor(rs, 4); rs += __shfl_xor(rs, 8);
  if (psub == 0) rowsum[prow] = rs;
  __syncthreads();
  // ---- epilogue: normalize + elu + store ----
#pragma unroll
  for (int m = 0; m < 2; ++m)
#pragma unroll
    for (int n = 0; n < 2; ++n)
#pragma unroll
      for (int q = 0; q < 4; ++q) {
        int row = m * 16 + lq * 4 + q;
        int grow = r0 + row;
        if (grow < NN) {
          float v = acc[m][n][q] / rowsum[row];
          float o = (v > 0.f) ? v : (__expf(v) - 1.f);
          out[(size_t)grow * FOUT + w * 32 + n * 16 + lr] = o;
        }
      }
}

extern "C" void kernel_launch(void* const* d_in, const int* in_sizes, int n_in,
                              void* d_out, int out_size, void* d_ws, size_t ws_size,
                              hipStream_t stream) {
  const float* h   = (const float*)d_in[0];
  const int*   adj = (const int*)d_in[1];
  const float* W   = (const float*)d_in[2];
  const float* a   = (const float*)d_in[3];
  float* out = (float*)d_out;
  char* ws = (char*)d_ws;
  // ws layout (all 256B aligned):
  _Float16* Wt  = (_Float16*)(ws + 0);          // 256*512*2   =   262144
  float*    Wh  = (float*)(ws + 262144);        // 10000*256*4 = 10240000
  short*    WhT = (short*)(ws + 10502144);      // 256*10048*2 =  5144576
  float*    e1  = (float*)(ws + 15646720);      // 10048*4
  float*    e2  = (float*)(ws + 15686912);      // 10048*4  (end: 15727104)
  (void)in_sizes; (void)n_in; (void)out_size; (void)ws_size;

  k0_wt<<<dim3(512), dim3(256), 0, stream>>>(W, Wt);
  k1_wh<<<dim3(157), dim3(256), 0, stream>>>(h, Wt, Wh);
  k2_et<<<dim3(157), dim3(256), 0, stream>>>(Wh, a, e1, e2, WhT);
  k3_main<<<dim3(313), dim3(512), 0, stream>>>(adj, e1, e2, WhT, out);
}